// Round 5
// baseline (2056.714 us; speedup 1.0000x reference)
//
#include <hip/hip_runtime.h>
#include <math.h>

// ---------------------------------------------------------------------------
// Transpose all 32 weight matrices: wt[mat][c][k] = W[mat>>1][k][c]  (f32)
// mat = (l*8+t)*2 + which (0=Wl, 1=Wr)
// ---------------------------------------------------------------------------
__global__ __launch_bounds__(256) void transpose_w(
    const float* __restrict__ Wl, const float* __restrict__ Wr,
    float* __restrict__ wt)
{
  int elem = blockIdx.x * 256 + threadIdx.x;   // 0 .. 32*16384-1
  int mat = elem >> 14;
  int c = (elem >> 7) & 127;
  int k = elem & 127;
  const float* srcb = (mat & 1) ? Wr : Wl;
  int m2 = mat >> 1;
  wt[elem] = srcb[((long)m2 << 14) + (k << 7) + c];
}

// ---------------------------------------------------------------------------
// proj_v2: out[N,128] = x[N,128] @ W[128,128], W transposed wt[c][k].
// 64 rows x 128 cols per block (256 thr); per thread 8 rows x 4 cols.
// Per 4-k chunk: 8 LDS b128 (row-broadcast, conflict-free) + 4 global b128
// (L2-resident W) feeding 128 FMAs -> FMA-bound. ACC: += into out.
// ---------------------------------------------------------------------------
template<bool ACC>
__global__ __launch_bounds__(256) void proj_v2(
    const float* __restrict__ xg, const float* __restrict__ wtg,
    float* __restrict__ out, int N)
{
  __shared__ __align__(16) float xs[64][128];
  const int tid = threadIdx.x;
  const long r0 = (long)blockIdx.x * 64;
  for (int i = tid; i < 2048; i += 256) {   // 64 rows x 32 float4
    int r = i >> 5, c4 = (i & 31) << 2;
    float4 v = {0.f, 0.f, 0.f, 0.f};
    if (r0 + r < N) v = *(const float4*)(xg + (r0 + r) * 128 + c4);
    *(float4*)&xs[r][c4] = v;
  }
  __syncthreads();
  const int rb = (tid >> 5) * 8, cb = (tid & 31) * 4;
  float acc[8][4] = {};
  for (int kc = 0; kc < 32; ++kc) {
    int k = kc << 2;
    float4 w0 = *(const float4*)(wtg + (cb + 0) * 128 + k);
    float4 w1 = *(const float4*)(wtg + (cb + 1) * 128 + k);
    float4 w2 = *(const float4*)(wtg + (cb + 2) * 128 + k);
    float4 w3 = *(const float4*)(wtg + (cb + 3) * 128 + k);
#pragma unroll
    for (int r = 0; r < 8; ++r) {
      float4 xv = *(const float4*)&xs[rb + r][k];
      acc[r][0] = fmaf(xv.x, w0.x, fmaf(xv.y, w0.y, fmaf(xv.z, w0.z, fmaf(xv.w, w0.w, acc[r][0]))));
      acc[r][1] = fmaf(xv.x, w1.x, fmaf(xv.y, w1.y, fmaf(xv.z, w1.z, fmaf(xv.w, w1.w, acc[r][1]))));
      acc[r][2] = fmaf(xv.x, w2.x, fmaf(xv.y, w2.y, fmaf(xv.z, w2.z, fmaf(xv.w, w2.w, acc[r][2]))));
      acc[r][3] = fmaf(xv.x, w3.x, fmaf(xv.y, w3.y, fmaf(xv.z, w3.z, fmaf(xv.w, w3.w, acc[r][3]))));
    }
  }
#pragma unroll
  for (int r = 0; r < 8; ++r) {
    long row = r0 + rb + r;
    if (row < N) {
      float* op = out + row * 128 + cb;
      if (ACC) {
        float4 cur = *(const float4*)op;
        cur.x += acc[r][0]; cur.y += acc[r][1];
        cur.z += acc[r][2]; cur.w += acc[r][3];
        *(float4*)op = cur;
      } else {
        float4 v = {acc[r][0], acc[r][1], acc[r][2], acc[r][3]};
        *(float4*)op = v;
      }
    }
  }
}

// ---------------------------------------------------------------------------
// Batched CSR build over all 5 edge types (3 launches total).
// ---------------------------------------------------------------------------
struct EdgeArgs {
  const int* src[5]; const int* dst[5];
  int* cur[5];         // degree, then cursor (aliased)
  int* rs[5];          // row_start[nd+1]
  int* csrc[5];
  int E[5]; int Nd[5];
  int blkOff[6];       // block-range per type for hist/fill grids
};

__global__ __launch_bounds__(256) void hist_all(EdgeArgs a)
{
  int blk = blockIdx.x, t = 0;
  while (blk >= a.blkOff[t + 1]) ++t;
  int e = (blk - a.blkOff[t]) * 256 + threadIdx.x;
  if (e < a.E[t]) atomicAdd(&a.cur[t][a.dst[t][e]], 1);
}

__global__ __launch_bounds__(1024) void scan_all(EdgeArgs a)
{
  int t = blockIdx.x;
  int n = a.Nd[t];
  int* deg = a.cur[t];
  int* rs = a.rs[t];
  __shared__ int tile[1024];
  __shared__ int sbase;
  int tid = threadIdx.x;
  if (tid == 0) sbase = 0;
  __syncthreads();
  for (int chunk = 0; chunk < n; chunk += 16384) {
    int idx0 = chunk + tid * 16;
    int v[16], sum = 0;
#pragma unroll
    for (int j = 0; j < 16; ++j) {
      v[j] = (idx0 + j < n) ? deg[idx0 + j] : 0;
      sum += v[j];
    }
    tile[tid] = sum;
    __syncthreads();
    for (int off = 1; off < 1024; off <<= 1) {   // Hillis-Steele inclusive
      int tv = (tid >= off) ? tile[tid - off] : 0;
      __syncthreads();
      tile[tid] += tv;
      __syncthreads();
    }
    int excl = sbase + ((tid > 0) ? tile[tid - 1] : 0);
#pragma unroll
    for (int j = 0; j < 16; ++j) {
      if (idx0 + j < n) { rs[idx0 + j] = excl; deg[idx0 + j] = excl; }
      excl += v[j];
    }
    __syncthreads();
    if (tid == 0) sbase += tile[1023];
    __syncthreads();
  }
  if (tid == 0) rs[n] = sbase;
}

__global__ __launch_bounds__(256) void fill_all(EdgeArgs a)
{
  int blk = blockIdx.x, t = 0;
  while (blk >= a.blkOff[t + 1]) ++t;
  int e = (blk - a.blkOff[t]) * 256 + threadIdx.x;
  if (e < a.E[t]) {
    int pos = atomicAdd(&a.cur[t][a.dst[t][e]], 1);
    a.csrc[t][pos] = a.src[t][e];
  }
}

// ---------------------------------------------------------------------------
// Fused GATv2 aggregate, one wave per dst row. Lane l owns channels 2l,2l+1;
// head h = lanes [8h,8h+8). agg[d] (=|+=) (sum_e a_e*hs[src_e])/(sum_e a_e+eps).
// INIT: plain store (first edge type writing this dst type -> no agg memset).
// ---------------------------------------------------------------------------
template<bool INIT>
__global__ __launch_bounds__(256) void gat_gather(
    const int* __restrict__ row_start, const int* __restrict__ csr_src,
    const float* __restrict__ hs, const float* __restrict__ hd,
    const float* __restrict__ att, float* __restrict__ agg, int Nd)
{
  int d = blockIdx.x * 4 + (threadIdx.x >> 6);
  if (d >= Nd) return;
  int lane = threadIdx.x & 63;
  float2 att2 = *(const float2*)(att + 2 * lane);
  float2 hd2 = *(const float2*)(hd + (long)d * 128 + 2 * lane);
  int beg = row_start[d], end = row_start[d + 1];
  float n0 = 0.f, n1 = 0.f, D = 0.f;
  int i = beg;
  int sNext = (i < end) ? csr_src[i] : 0;
  for (; i < end; ++i) {
    int s = sNext;
    if (i + 1 < end) sNext = csr_src[i + 1];
    float2 h = *(const float2*)(hs + (long)s * 128 + 2 * lane);
    float v0 = h.x + hd2.x, v1 = h.y + hd2.y;
    v0 = fmaxf(v0, 0.2f * v0);
    v1 = fmaxf(v1, 0.2f * v1);
    float pp = fmaf(v0, att2.x, v1 * att2.y);
    pp += __shfl_xor(pp, 1);
    pp += __shfl_xor(pp, 2);
    pp += __shfl_xor(pp, 4);          // 8 lanes of the head hold the logit
    float a = expf(fminf(pp, 60.f));
    n0 = fmaf(a, h.x, n0);
    n1 = fmaf(a, h.y, n1);
    D += a;
  }
  float inv = 1.f / (D + 1e-16f);
  float* ap = agg + (long)d * 128 + 2 * lane;
  if (INIT) {
    float2 v = {n0 * inv, n1 * inv};
    *(float2*)ap = v;
  } else {
    float2 cur = *(const float2*)ap;
    cur.x += n0 * inv;
    cur.y += n1 * inv;
    *(float2*)ap = cur;
  }
}

// ---------------------------------------------------------------------------
// xf = LayerNorm(xin + elu(agg + sum_masked(bias)));  1 wave per row.
// ---------------------------------------------------------------------------
__global__ __launch_bounds__(256) void update_ln(
    const float* __restrict__ xin, float* __restrict__ xf,
    const float* __restrict__ agg, const float* __restrict__ biasl, int tmask,
    const float* __restrict__ gam, const float* __restrict__ bet, int N)
{
  int row = blockIdx.x * 4 + (threadIdx.x >> 6);
  int lane = threadIdx.x & 63;
  if (row >= N) return;
  float bs0 = 0.f, bs1 = 0.f;
#pragma unroll
  for (int t = 0; t < 8; ++t)
    if (tmask & (1 << t)) {
      bs0 += biasl[t * 128 + lane];
      bs1 += biasl[t * 128 + 64 + lane];
    }
  long base = (long)row * 128;
  float v0 = agg[base + lane] + bs0, v1 = agg[base + 64 + lane] + bs1;
  v0 = v0 > 0.f ? v0 : expf(v0) - 1.f;
  v1 = v1 > 0.f ? v1 : expf(v1) - 1.f;
  float x0 = xin[base + lane] + v0, x1 = xin[base + 64 + lane] + v1;
  float s = x0 + x1;
#pragma unroll
  for (int o = 32; o > 0; o >>= 1) s += __shfl_xor(s, o);
  float mu = s * 0.0078125f;
  float dd0 = x0 - mu, dd1 = x1 - mu;
  float q = dd0 * dd0 + dd1 * dd1;
#pragma unroll
  for (int o = 32; o > 0; o >>= 1) q += __shfl_xor(q, o);
  float r = rsqrtf(q * 0.0078125f + 1e-5f);
  xf[base + lane]      = dd0 * r * gam[lane]      + bet[lane];
  xf[base + 64 + lane] = dd1 * r * gam[64 + lane] + bet[64 + lane];
}

// ---------------------------------------------------------------------------
// zgemm stage 1: grid-strided partial tiles, NO atomics.
// zpart[blk][64][128] = sum over assigned 64-row n-chunks of batch^T-chunk @ x-chunk
// ---------------------------------------------------------------------------
__global__ __launch_bounds__(256) void zgemm_part(
    const float* __restrict__ batch, const float* __restrict__ x,
    float* __restrict__ zpart, int N, int G)
{
  __shared__ __align__(16) float xl[64 * 128];
  __shared__ __align__(16) float bl[64 * 65];
  int tid = threadIdx.x;
  int nch = (N + 63) / 64;
  int cg = (tid & 31) * 4;
  int bg = (tid >> 5) * 8;
  float acc[8][4] = {};
  for (int ch = blockIdx.x; ch < nch; ch += G) {
    int n0 = ch * 64;
    __syncthreads();
    for (int i = tid; i < 64 * 128; i += 256) {
      int nn = i >> 7;
      xl[i] = (n0 + nn < N) ? x[(long)(n0 + nn) * 128 + (i & 127)] : 0.f;
    }
    for (int i = tid; i < 64 * 64; i += 256) {
      int b = i >> 6, nn = i & 63;
      bl[nn * 65 + b] = (n0 + nn < N) ? batch[(long)b * N + n0 + nn] : 0.f;
    }
    __syncthreads();
    for (int nn = 0; nn < 64; ++nn) {
      float4 xv = *(const float4*)(xl + nn * 128 + cg);
#pragma unroll
      for (int i = 0; i < 8; ++i) {
        float bv = bl[nn * 65 + bg + i];
        acc[i][0] = fmaf(bv, xv.x, acc[i][0]);
        acc[i][1] = fmaf(bv, xv.y, acc[i][1]);
        acc[i][2] = fmaf(bv, xv.z, acc[i][2]);
        acc[i][3] = fmaf(bv, xv.w, acc[i][3]);
      }
    }
  }
  float* zp = zpart + (long)blockIdx.x * 8192;
#pragma unroll
  for (int i = 0; i < 8; ++i) {
#pragma unroll
    for (int j = 0; j < 4; ++j) {
      // non-atomic: each block owns its partial tile
      zp[(bg + i) * 128 + cg + j] = acc[i][j];
    }
  }
}

// ---------------------------------------------------------------------------
// zgemm stage 2: zpre[ty][i] = scale[ty] * sum_g zpart[ty][g][i]
// grid 96 blocks x 256 (ty = blk>>5).
// ---------------------------------------------------------------------------
__global__ __launch_bounds__(256) void zreduce(
    const float* __restrict__ zp0, const float* __restrict__ zp1,
    const float* __restrict__ zp2, int G0, int G1, int G2,
    float s0, float s1, float s2, float* __restrict__ zpre)
{
  int blk = blockIdx.x;
  int ty = blk >> 5;
  int i = (blk & 31) * 256 + threadIdx.x;
  const float* zp = ty == 0 ? zp0 : (ty == 1 ? zp1 : zp2);
  int G = ty == 0 ? G0 : (ty == 1 ? G1 : G2);
  float sc = ty == 0 ? s0 : (ty == 1 ? s1 : s2);
  float s = 0.f;
  for (int g = 0; g < G; ++g) s += zp[(long)g * 8192 + i];
  zpre[ty * 8192 + i] = s * sc;
}

// ---------------------------------------------------------------------------
// Final LayerNorm over zpre[3*64,128] -> f32 out. 1 wave/row.
// ---------------------------------------------------------------------------
__global__ __launch_bounds__(256) void final_ln(
    const float* __restrict__ zpre, const float* __restrict__ gam,
    const float* __restrict__ bet, float* __restrict__ out)
{
  int row = blockIdx.x * 4 + (threadIdx.x >> 6);
  int lane = threadIdx.x & 63;
  if (row >= 192) return;
  int ty = row >> 6;
  long base = (long)row * 128;
  float x0 = zpre[base + lane], x1 = zpre[base + 64 + lane];
  float s = x0 + x1;
#pragma unroll
  for (int o = 32; o > 0; o >>= 1) s += __shfl_xor(s, o);
  float mu = s * 0.0078125f;
  float d0 = x0 - mu, d1 = x1 - mu;
  float q = d0 * d0 + d1 * d1;
#pragma unroll
  for (int o = 32; o > 0; o >>= 1) q += __shfl_xor(q, o);
  float r = rsqrtf(q * 0.0078125f + 1e-5f);
  out[base + lane]      = d0 * r * gam[ty * 128 + lane]      + bet[ty * 128 + lane];
  out[base + 64 + lane] = d1 * r * gam[ty * 128 + 64 + lane] + bet[ty * 128 + 64 + lane];
}

// ---------------------------------------------------------------------------
extern "C" void kernel_launch(void* const* d_in, const int* in_sizes, int n_in,
                              void* d_out, int out_size, void* d_ws, size_t ws_size,
                              hipStream_t stream)
{
  const float* batchp[3] = {(const float*)d_in[0], (const float*)d_in[1],
                            (const float*)d_in[2]};
  const float* emb[3] = {(const float*)d_in[3], (const float*)d_in[4],
                         (const float*)d_in[5]};
  const float* Wl   = (const float*)d_in[6];
  const float* Wr   = (const float*)d_in[7];
  const float* att  = (const float*)d_in[8];
  const float* bias = (const float*)d_in[9];
  const float* lng  = (const float*)d_in[10];
  const float* lnb  = (const float*)d_in[11];
  const float* outg = (const float*)d_in[12];
  const float* outb = (const float*)d_in[13];
  const int* eiP[8]; int E[8];
  for (int t = 0; t < 8; ++t) { eiP[t] = (const int*)d_in[14 + t]; E[t] = in_sizes[14 + t] / 2; }
  int Nn[3] = {in_sizes[3] / 128, in_sizes[4] / 128, in_sizes[5] / 128};
  int maxN = Nn[0] > Nn[1] ? Nn[0] : Nn[1]; if (Nn[2] > maxN) maxN = Nn[2];
  long Ntot = (long)Nn[0] + Nn[1] + Nn[2];

  const int SI[5] = {1, 0, 2, 0, 0};
  const int DI[5] = {0, 1, 0, 2, 0};
  const int TMASK[3] = {0x35, 0x42, 0x88};  // gene: t0,t2,t4,t5; cpg: t1,t6; mirna: t3,t7

  char* p = (char*)d_ws;
  auto carve = [&](size_t b) -> void* {
    void* r = (void*)p; p += (b + 255) & ~(size_t)255; return r;
  };
  float* xf[3];
  for (int ty = 0; ty < 3; ++ty) xf[ty] = (float*)carve((size_t)Nn[ty] * 128 * 4);
  float* aggAll = (float*)carve((size_t)Ntot * 128 * 4);
  float* agg[3] = {aggAll, aggAll + (long)Nn[0] * 128, aggAll + ((long)Nn[0] + Nn[1]) * 128};
  float* hsb = (float*)carve((size_t)maxN * 128 * 4);
  float* hdb = (float*)carve((size_t)maxN * 128 * 4);
  float* zpre = (float*)carve(3 * 64 * 128 * 4);
  float* wt = (float*)carve((size_t)32 * 16384 * 4);

  // CSR (deg/cursor regions contiguous for one memset)
  EdgeArgs ea;
  long degTot = 0;
  for (int t = 0; t < 5; ++t) degTot += Nn[DI[t]];
  int* degAll = (int*)carve(degTot * 4);
  {
    int* dp = degAll;
    int boff = 0;
    for (int t = 0; t < 5; ++t) {
      int nd = Nn[DI[t]];
      ea.src[t] = eiP[t];
      ea.dst[t] = eiP[t] + E[t];
      ea.cur[t] = dp; dp += nd;
      ea.rs[t] = (int*)carve((size_t)(nd + 1) * 4);
      ea.csrc[t] = (int*)carve((size_t)E[t] * 4);
      ea.E[t] = E[t];
      ea.Nd[t] = nd;
      ea.blkOff[t] = boff;
      boff += (E[t] + 255) / 256;
      if (t == 4) ea.blkOff[5] = boff;
    }
  }
  if ((size_t)(p - (char*)d_ws) > ws_size) return;  // workspace too small

  // zgemm partials alias hsb/hdb (dead after the layer loop): 3 x 128 x 32 KB
  const int GMAX = 128;
  float* zp[3];
  for (int ty = 0; ty < 3; ++ty) zp[ty] = hsb + (long)ty * GMAX * 8192;
  int Gty[3];
  for (int ty = 0; ty < 3; ++ty) {
    int nch = (Nn[ty] + 63) / 64;
    Gty[ty] = nch < GMAX ? nch : GMAX;
  }

  // 0) transpose weights
  transpose_w<<<2048, 256, 0, stream>>>(Wl, Wr, wt);

  // 1) build CSR for the 5 real edge types (3 launches)
  hipMemsetAsync(degAll, 0, degTot * 4, stream);
  hist_all<<<ea.blkOff[5], 256, 0, stream>>>(ea);
  scan_all<<<5, 1024, 0, stream>>>(ea);
  fill_all<<<ea.blkOff[5], 256, 0, stream>>>(ea);

  for (int l = 0; l < 2; ++l) {
    const float* xin[3] = {l == 0 ? emb[0] : xf[0],
                           l == 0 ? emb[1] : xf[1],
                           l == 0 ? emb[2] : xf[2]};
    for (int t = 0; t < 5; ++t) {
      int si = SI[t], di = DI[t];
      int mb = (l * 8 + t) * 2;
      proj_v2<false><<<(Nn[si] + 63) / 64, 256, 0, stream>>>(
          xin[si], wt + (long)mb * 16384, hsb, Nn[si]);
      proj_v2<false><<<(Nn[di] + 63) / 64, 256, 0, stream>>>(
          xin[di], wt + (long)(mb + 1) * 16384, hdb, Nn[di]);
      const float* attp = att + (long)(l * 8 + t) * 128;
      int gblk = (Nn[di] + 3) / 4;
      if (t == 0 || t == 1 || t == 3)   // first writer of gene/cpg/mirna agg
        gat_gather<true><<<gblk, 256, 0, stream>>>(
            ea.rs[t], ea.csrc[t], hsb, hdb, attp, agg[di], Nn[di]);
      else
        gat_gather<false><<<gblk, 256, 0, stream>>>(
            ea.rs[t], ea.csrc[t], hsb, hdb, attp, agg[di], Nn[di]);
    }
    for (int t = 5; t < 8; ++t) {  // self-loop convs: agg += x @ Wl (alpha == 1)
      int ty = t - 5;
      proj_v2<true><<<(Nn[ty] + 63) / 64, 256, 0, stream>>>(
          xin[ty], wt + (long)((l * 8 + t) * 2) * 16384, agg[ty], Nn[ty]);
    }
    for (int ty = 0; ty < 3; ++ty)
      update_ln<<<(Nn[ty] + 3) / 4, 256, 0, stream>>>(
          xin[ty], xf[ty], agg[ty], bias + (long)l * 8 * 128, TMASK[ty],
          lng + (long)(l * 3 + ty) * 128, lnb + (long)(l * 3 + ty) * 128, Nn[ty]);
  }

  // final: z = LN(batch @ x / sqrt(N)) via non-atomic partials + reduce
  for (int ty = 0; ty < 3; ++ty)
    zgemm_part<<<Gty[ty], 256, 0, stream>>>(batchp[ty], xf[ty], zp[ty], Nn[ty], Gty[ty]);
  zreduce<<<96, 256, 0, stream>>>(
      zp[0], zp[1], zp[2], Gty[0], Gty[1], Gty[2],
      (float)(1.0 / sqrt((double)Nn[0])), (float)(1.0 / sqrt((double)Nn[1])),
      (float)(1.0 / sqrt((double)Nn[2])), zpre);
  final_ln<<<48, 256, 0, stream>>>(zpre, outg, outb, (float*)d_out);
}